// Round 12
// baseline (98.686 us; speedup 1.0000x reference)
//
#include <hip/hip_runtime.h>
#include <hip/hip_bf16.h>
#include <stdint.h>

// Problem constants
#define BATCH 16
#define IN_CH 64
#define HIN 56
#define WIN_ 56
#define HO 54
#define WO 54
#define P_PER_B (HO*WO)        // 2916
#define P_PAD 2944             // 23 * 128
#define OUT_CH 256
#define KDIM 576               // 64*3*3
#define NPIX (HIN*WIN_)        // 3136
#define XT_PIX 3264            // padded pixel rows per batch (A-region staging overrun)

typedef __attribute__((ext_vector_type(8))) short short8;
typedef __attribute__((ext_vector_type(4))) float f32x4;

__device__ __forceinline__ unsigned short f2bf(float f) {
    unsigned int u = __float_as_uint(f);
    unsigned int r = (u + 0x7fffu + ((u >> 16) & 1u)) >> 16;   // RNE
    return (unsigned short)r;
}

// ---------------- merged prep kernel ----------------
// One dispatch, heterogeneous blocks:
//  blocks [0,64):    weight prep — 4 output channels per block (64 lanes each):
//                    bf16-convert into TAP-MAJOR wbf[tap][o][c] + ||w_o||^2.
//  blocks [64,848):  NCHW f32 -> NHWC bf16 transpose (64 pix x 64 ch) with
//                    float4 loads + fused per-pixel channel square-sum s[b,pix].
__global__ __launch_bounds__(256) void prep_merged(
    const float* __restrict__ w, short* __restrict__ wbf, float* __restrict__ c2,
    const float* __restrict__ x, short* __restrict__ xT, float* __restrict__ s) {
    __shared__ short lds[64 * 65];
    __shared__ float red4[256 * 4];            // [cq][pixgrp][4]

    if (blockIdx.x < 64) {
        // ---- weight prep: o = blockIdx.x*4 + quarter ----
        const int o = blockIdx.x * 4 + (threadIdx.x >> 6);
        const int lane = threadIdx.x & 63;
        float sw = 0.f;
        #pragma unroll
        for (int j = 0; j < 9; ++j) {          // 576 = 9*64
            int k = j * 64 + lane;             // original k = c*9 + tap
            int c = k / 9, tap = k % 9;
            float v = w[o * KDIM + k];
            sw += v * v;
            ((unsigned short*)wbf)[((size_t)tap * OUT_CH + o) * 64 + c] = f2bf(v);
        }
        #pragma unroll
        for (int off = 32; off > 0; off >>= 1) sw += __shfl_down(sw, off);
        if (lane == 0) c2[o] = sw;
        return;
    }

    const int blk  = blockIdx.x - 64;          // 0..783
    const int b    = blk / 49;
    const int pix0 = (blk % 49) * 64;
    const int tid  = threadIdx.x;
    const int cq = tid >> 4;                   // 0..15 channel group
    const int pg = tid & 15;                   // 0..15 pixel group (4 pix each)
    const float* xb = x + (size_t)b * IN_CH * NPIX + pix0 + pg * 4;
    f32x4 accp = (f32x4){0.f, 0.f, 0.f, 0.f};
    #pragma unroll
    for (int it = 0; it < 4; ++it) {
        int c = it * 16 + cq;
        f32x4 v = *(const f32x4*)(xb + (size_t)c * NPIX);  // 16-B aligned
        #pragma unroll
        for (int j = 0; j < 4; ++j) {
            accp[j] += v[j] * v[j];
            lds[(pg * 4 + j) * 65 + c] = (short)f2bf(v[j]);
        }
    }
    *(f32x4*)(red4 + tid * 4) = accp;
    __syncthreads();
    const int cs = tid & 63;
    const int quarter = tid >> 6;
    short* xTb = xT + ((size_t)b * XT_PIX + pix0) * 64;
    #pragma unroll
    for (int it = 0; it < 16; ++it) {
        int pixs = quarter * 16 + it;
        xTb[(size_t)pixs * 64 + cs] = lds[pixs * 65 + cs];  // wave writes 128B contiguous
    }
    if (tid < 64) {
        float sacc = 0.f;
        #pragma unroll
        for (int c16 = 0; c16 < 16; ++c16)
            sacc += red4[(c16 * 16 + (tid >> 2)) * 4 + (tid & 3)];
        s[b * NPIX + pix0 + tid] = sacc;
    }
}

// ---------------- fused im2col GEMM + RBF epilogue ----------------
// R11 measured-best structure + A-fragment rotation: the ks=0 A-fragments of
// tap kt+1 are ds_read BEFORE the per-tap vmcnt/barrier and fly across it
// (raw s_barrier drains neither lgkmcnt nor the DS pipe; lds_a is written once
// and stable) -> ~4 reads of each tap's serial chain overlap the barrier wait.
// sched_barrier(0) still pins the lds_b reads below the barrier.

#define AS1(p) ((const __attribute__((address_space(1))) void*)(p))
#define AS3(p) ((__attribute__((address_space(3))) void*)(p))

__global__ __launch_bounds__(512, 4) void gemm_rbf(
    const short* __restrict__ xT, const short* __restrict__ wbf,
    const float* __restrict__ s, const float* __restrict__ c2,
    float* __restrict__ out) {
    __shared__ __align__(16) short lds_a[352 * 64];      // 45 KB pixel region, swizzled
    __shared__ __align__(16) short lds_b[2 * 128 * 64];  // 2 x 16 KB per-tap B tiles

    const int bx = blockIdx.x;                 // 0..367
    const int mt = (bx & 7) * 46 + (bx >> 3);  // XCD-chunked, bijective (368=8*46)
    const int b  = mt / 23;
    const int p0 = (mt % 23) * 128;
    const int n0 = blockIdx.y * 128;

    const int tid  = threadIdx.x;              // 0..511
    const int wave = tid >> 6;                 // 0..7
    const int lane = tid & 63;
    const int r16  = lane & 15;
    const int quad = lane >> 4;
    const int wm = (wave >> 2) * 64;           // 0 or 64
    const int wn = (wave & 3) * 32;            // 0,32,64,96

    const int oh_base  = p0 / WO;
    const int ihw_base = oh_base * WIN_;

    // staging lane mapping: 8 lanes per 128-B row, 16 B per lane.
    // physical chunk (lane&7) of lds row r holds logical chunk (lane&7)^(r&7).
    const int srow = lane >> 3;                // 0..7
    const int scx  = (lane & 7) ^ srow;        // pre-swizzled source chunk

    // ---- A-region staging (ONCE): 352 rows from xT, contiguous pixels ----
    const short* aSrc = xT + ((size_t)b * XT_PIX + ihw_base + srow) * 64 + scx * 8;
    #pragma unroll
    for (int i = 0; i < 6; ++i) {              // 8 waves x 6 x 8 rows, guard at 352
        int rb8 = (wave * 6 + i) * 8;
        if (rb8 < 352)
            __builtin_amdgcn_global_load_lds(AS1(aSrc + (size_t)rb8 * 64),
                                             AS3(lds_a + rb8 * 64), 16, 0, 0);
    }
    // ---- B staging base (tap-major wbf: [tap][o][c]) ----
    const short* gbB = wbf + ((size_t)n0 + wave * 16 + srow) * 64 + scx * 8;
    #pragma unroll
    for (int i = 0; i < 2; ++i)                // tap 0 into buffer 0
        __builtin_amdgcn_global_load_lds(AS1(gbB + (size_t)i * 8 * 64),
                                         AS3(lds_b + (wave * 2 + i) * 512), 16, 0, 0);

    // per-fragment-row pixel index relative to the staged region (pad rows clamped;
    // their D rows are discarded in the store phase)
    int ihw_rel[4];
    #pragma unroll
    for (int ms = 0; ms < 4; ++ms) {
        int p = p0 + wm + ms * 16 + r16;
        if (p > P_PER_B - 1) p = P_PER_B - 1;
        int oh = p / WO, ow = p - oh * WO;
        ihw_rel[ms] = oh * WIN_ + ow - ihw_base;   // 0..221
    }
    const int xq = r16 & 7;                    // B fragment-read swizzle key

    // ---- in-prologue w2 = 3x3 window sum of s (replaces w2_kernel) ----
    const int ecol = tid & 31;                 // f32x4 column within 512-B run
    const int erow = tid >> 5;                 // 0..15
    const int pcol = p0 + ecol * 4;
    const bool pok = (pcol < P_PER_B);         // aligned: P_PER_B % 4 == 0
    f32x4 w2v;
    {
        const int pbase = pok ? pcol : (P_PER_B - 4);
        const float* sb = s + b * NPIX;
        #pragma unroll
        for (int r = 0; r < 4; ++r) {
            int p = pbase + r;
            int oh = p / WO, ow = p - oh * WO;
            const float* sp = sb + oh * WIN_ + ow;
            float a0 = 0.f;
            #pragma unroll
            for (int kh = 0; kh < 3; ++kh)
                #pragma unroll
                for (int kw = 0; kw < 3; ++kw)
                    a0 += sp[kh * WIN_ + kw];   // same summation order as w2_kernel
            w2v[r] = a0;
        }
    }

    f32x4 acc[4][2];
    #pragma unroll
    for (int i = 0; i < 4; ++i)
        #pragma unroll
        for (int j = 0; j < 2; ++j)
            acc[i][j] = (f32x4){0.f, 0.f, 0.f, 0.f};

    // initial sync: A region + B tap0 resident
    asm volatile("s_waitcnt vmcnt(0)" ::: "memory");
    __builtin_amdgcn_s_barrier();
    __builtin_amdgcn_sched_barrier(0);

    // preload ks=0 A-fragments for tap 0 (lds_a stable for the whole K-loop)
    short8 afp[4];
    #pragma unroll
    for (int ms = 0; ms < 4; ++ms) {
        int rl = ihw_rel[ms];                  // + dtab[0] = 0
        afp[ms] = *(const short8*)(lds_a + rl * 64 + ((quad ^ (rl & 7)) * 8));
    }

    constexpr int dtab_l[9] = {0, 1, 2, 56, 57, 58, 112, 113, 114};  // kh*56+kw
    #pragma unroll
    for (int kt = 0; kt < 9; ++kt) {
        if (kt < 8) {                          // issue next tap's B under this tap's MFMAs
            short* dstB = lds_b + ((kt + 1) & 1) * (128 * 64);
            #pragma unroll
            for (int i = 0; i < 2; ++i)
                __builtin_amdgcn_global_load_lds(
                    AS1(gbB + ((size_t)(kt + 1) * OUT_CH + i * 8) * 64),
                    AS3(dstB + (wave * 2 + i) * 512), 16, 0, 0);
        }
        const short* lb = lds_b + (kt & 1) * (128 * 64);
        const int dt = dtab_l[kt];
        __builtin_amdgcn_s_setprio(1);
        // ks = 0: A-fragments preloaded (afp), issued before the barrier
        {
            short8 bfr[2];
            #pragma unroll
            for (int ns = 0; ns < 2; ++ns)
                bfr[ns] = *(const short8*)(lb + (wn + ns * 16 + r16) * 64
                                              + ((quad ^ xq) * 8));
            #pragma unroll
            for (int ms = 0; ms < 4; ++ms)
                #pragma unroll
                for (int ns = 0; ns < 2; ++ns)
                    acc[ms][ns] = __builtin_amdgcn_mfma_f32_16x16x32_bf16(
                        afp[ms], bfr[ns], acc[ms][ns], 0, 0, 0);
        }
        // ks = 1: inline reads (compiler overlaps with ks=0 MFMAs)
        {
            short8 af1[4], bfr[2];
            #pragma unroll
            for (int ms = 0; ms < 4; ++ms) {
                int rl = ihw_rel[ms] + dt;
                af1[ms] = *(const short8*)(lds_a + rl * 64
                                                 + (((4 + quad) ^ (rl & 7)) * 8));
            }
            #pragma unroll
            for (int ns = 0; ns < 2; ++ns)
                bfr[ns] = *(const short8*)(lb + (wn + ns * 16 + r16) * 64
                                              + (((4 + quad) ^ xq) * 8));
            #pragma unroll
            for (int ms = 0; ms < 4; ++ms)
                #pragma unroll
                for (int ns = 0; ns < 2; ++ns)
                    acc[ms][ns] = __builtin_amdgcn_mfma_f32_16x16x32_bf16(
                        af1[ms], bfr[ns], acc[ms][ns], 0, 0, 0);
        }
        __builtin_amdgcn_s_setprio(0);
        if (kt < 8) {
            // rotate: read NEXT tap's ks=0 A-fragments BEFORE the barrier so the
            // ds_reads execute during the barrier wait (s_barrier drains nothing)
            const int dn = dtab_l[kt + 1];
            #pragma unroll
            for (int ms = 0; ms < 4; ++ms) {
                int rl = ihw_rel[ms] + dn;
                afp[ms] = *(const short8*)(lds_a + rl * 64
                                                 + ((quad ^ (rl & 7)) * 8));
            }
            asm volatile("s_waitcnt vmcnt(0)" ::: "memory");
            __builtin_amdgcn_s_barrier();
            __builtin_amdgcn_sched_barrier(0);
        }
    }

    // ---------------- coalesced RBF epilogue via LDS transpose ----------------
    // Two 64-channel chunks; owning waves dump acc into a padded [64][132] f32
    // tile (reusing lds_a); then all 512 threads stream channel-rows out as
    // contiguous 512-B runs.
    float* lf = (float*)lds_a;                 // 64*132*4 = 33.8 KB <= 45 KB
    const int myChunk = (wave >> 1) & 1;       // which 64-ch chunk this wave owns

    #pragma unroll
    for (int sc = 0; sc < 2; ++sc) {
        __syncthreads();                       // lds_a free / prev chunk consumed
        if (myChunk == sc) {
            #pragma unroll
            for (int ms = 0; ms < 4; ++ms) {
                int pl = wm + ms * 16 + quad * 4;
                #pragma unroll
                for (int ns = 0; ns < 2; ++ns) {
                    int od = (wave & 1) * 32 + ns * 16 + r16;   // 0..63 in chunk
                    *(f32x4*)(lf + od * 132 + pl) = acc[ms][ns];
                }
            }
        }
        __syncthreads();
        #pragma unroll
        for (int pass = 0; pass < 4; ++pass) {
            int row = pass * 16 + erow;        // 0..63
            int o   = n0 + sc * 64 + row;
            f32x4 a = *(const f32x4*)(lf + row * 132 + ecol * 4);
            float c2o = c2[o];
            f32x4 v;
            #pragma unroll
            for (int r = 0; r < 4; ++r) {
                float d2 = w2v[r] + c2o - 2.0f * a[r];
                d2 = fmaxf(d2, 1e-12f);
                v[r] = __expf(-0.125f * d2);
            }
            if (pok)
                *(f32x4*)(out + ((size_t)(b * OUT_CH + o)) * P_PER_B + pcol) = v;
        }
    }
}

// ---------------- launch ----------------

extern "C" void kernel_launch(void* const* d_in, const int* in_sizes, int n_in,
                              void* d_out, int out_size, void* d_ws, size_t ws_size,
                              hipStream_t stream) {
    const float* x = (const float*)d_in[0];    // [16,64,56,56]
    const float* w = (const float*)d_in[1];    // [256,576]
    float* out = (float*)d_out;                // [16,256,54,54]

    char* ws = (char*)d_ws;
    const size_t wbf_bytes = (size_t)OUT_CH * KDIM * 2;            // 294,912
    const size_t c2_bytes  = 1024;                                 // OUT_CH*4
    const size_t s_bytes   = (size_t)BATCH * NPIX * 4;             // 200,704
    short* wbf = (short*)ws;
    float* c2  = (float*)(ws + wbf_bytes);
    float* s   = (float*)(ws + wbf_bytes + c2_bytes);
    short* xT  = (short*)(ws + wbf_bytes + c2_bytes + s_bytes);    // 6.68 MB

    hipLaunchKernelGGL(prep_merged, dim3(64 + 16 * 49), dim3(256), 0, stream,
                       w, wbf, c2, x, xT, s);
    hipLaunchKernelGGL(gemm_rbf, dim3(23 * BATCH, OUT_CH / 128), dim3(512), 0, stream,
                       xT, wbf, s, c2, out);
}